// Round 2
// baseline (3792.925 us; speedup 1.0000x reference)
//
#include <hip/hip_runtime.h>
#include <stdint.h>

typedef unsigned short u16;
typedef __bf16 bf16x8 __attribute__((ext_vector_type(8)));
typedef float f32x4 __attribute__((ext_vector_type(4)));

constexpr int NB = 16384;        // batch tokens
constexpr int DM = 512;          // model dim
constexpr int NS = 4;            // streams
constexpr int FH = 2048;         // FFN hidden
constexpr int XW = NS * DM;      // 2048 concat width
constexpr float EPSL = 1e-5f;

__device__ __forceinline__ float bf2f(u16 u) { return __uint_as_float(((uint32_t)u) << 16); }
__device__ __forceinline__ u16 f2bf(float f) {
  uint32_t u = __float_as_uint(f);
  u += 0x7fffu + ((u >> 16) & 1u);
  return (u16)(u >> 16);
}
__device__ __forceinline__ void unpack8(uint4 p, float* f) {
  f[0] = __uint_as_float(p.x << 16); f[1] = __uint_as_float(p.x & 0xffff0000u);
  f[2] = __uint_as_float(p.y << 16); f[3] = __uint_as_float(p.y & 0xffff0000u);
  f[4] = __uint_as_float(p.z << 16); f[5] = __uint_as_float(p.z & 0xffff0000u);
  f[6] = __uint_as_float(p.w << 16); f[7] = __uint_as_float(p.w & 0xffff0000u);
}
__device__ __forceinline__ uint4 pack8(const float* f) {
  uint4 r;
  r.x = (uint32_t)f2bf(f[0]) | ((uint32_t)f2bf(f[1]) << 16);
  r.y = (uint32_t)f2bf(f[2]) | ((uint32_t)f2bf(f[3]) << 16);
  r.z = (uint32_t)f2bf(f[4]) | ((uint32_t)f2bf(f[5]) << 16);
  r.w = (uint32_t)f2bf(f[6]) | ((uint32_t)f2bf(f[7]) << 16);
  return r;
}
__device__ __forceinline__ void gl_lds16(const void* g, void* l) {
  __builtin_amdgcn_global_load_lds((const __attribute__((address_space(1))) void*)g,
                                   (__attribute__((address_space(3))) void*)l, 16, 0, 0);
}

// ---- shared GEMM main loop: 128x128 tile, BK=32, 256 threads, acc in regs ----
__device__ __forceinline__ void gemm_main(
    const u16* __restrict__ A, int lda, const u16* __restrict__ Bt, int K,
    u16* As, u16* Bs, f32x4 (&acc)[4][4])
{
  const int tid = threadIdx.x;
  const int ln = tid & 63;
  const int w  = tid >> 6;
  const int wm = w >> 1, wn = w & 1;
  const int m0 = blockIdx.x * 128;
  const int n0 = blockIdx.y * 128;
  const int sr = ln >> 2;
  const int sc = (ln & 3) * 8;
  const u16* Ab = A  + (size_t)(m0 + w * 32 + sr) * lda + sc;
  const u16* Bb = Bt + (size_t)(n0 + w * 32 + sr) * K   + sc;

  for (int k0 = 0; k0 < K; k0 += 32) {
#pragma unroll
    for (int i = 0; i < 2; ++i) {
      gl_lds16(Ab + (size_t)i * 16 * lda + k0, &As[(w * 32 + i * 16) * 32]);
      gl_lds16(Bb + (size_t)i * 16 * K   + k0, &Bs[(w * 32 + i * 16) * 32]);
    }
    __syncthreads();
    bf16x8 af[4], bfv[4];
#pragma unroll
    for (int m = 0; m < 4; ++m) {
      af[m]  = *(const bf16x8*)&As[(wm * 64 + m * 16 + (ln & 15)) * 32 + (ln >> 4) * 8];
      bfv[m] = *(const bf16x8*)&Bs[(wn * 64 + m * 16 + (ln & 15)) * 32 + (ln >> 4) * 8];
    }
#pragma unroll
    for (int m = 0; m < 4; ++m)
#pragma unroll
      for (int n = 0; n < 4; ++n)
        acc[m][n] = __builtin_amdgcn_mfma_f32_16x16x32_bf16(af[m], bfv[n], acc[m][n], 0, 0, 0);
    __syncthreads();
  }
}

// plain GEMM: C = A*Bt^T + bias [+Rsd][ReLU], bf16 or f32 out
template<bool RELU, bool RESID, bool OUTF32>
__global__ __launch_bounds__(256) void k_gemm(
    const u16* __restrict__ A, int lda, const u16* __restrict__ Bt,
    const float* __restrict__ bias, const u16* __restrict__ Rsd, int ldr,
    void* __restrict__ Cp, int ldc, int K)
{
  __shared__ alignas(16) u16 As[128 * 32];
  __shared__ alignas(16) u16 Bs[128 * 32];
  f32x4 acc[4][4] = {};
  gemm_main(A, lda, Bt, K, As, Bs, acc);
  const int ln = threadIdx.x & 63;
  const int w = threadIdx.x >> 6;
  const int wm = w >> 1, wn = w & 1;
  const int m0 = blockIdx.x * 128, n0 = blockIdx.y * 128;
#pragma unroll
  for (int n = 0; n < 4; ++n) {
    const int gc = n0 + wn * 64 + n * 16 + (ln & 15);
    const float bv = bias[gc];
#pragma unroll
    for (int m = 0; m < 4; ++m) {
#pragma unroll
      for (int j = 0; j < 4; ++j) {
        const int gr = m0 + wm * 64 + m * 16 + (ln >> 4) * 4 + j;
        float v = acc[m][n][j] + bv;
        if constexpr (RESID) v += bf2f(Rsd[(size_t)gr * ldr + gc]);
        if constexpr (RELU)  v = v > 0.f ? v : 0.f;
        if constexpr (OUTF32) ((float*)Cp)[(size_t)gr * ldc + gc] = v;
        else                  ((u16*)Cp)[(size_t)gr * ldc + gc] = f2bf(v);
      }
    }
  }
}

// V-projection with fused softmax weighting: ctx += w[b,h,kp] * (A*Wv^T + bv)
// MODE 0: first kp (no prev, f32 out); 1: mid (prev, f32 out); 2: last (prev, bf16 out)
template<int MODE>
__global__ __launch_bounds__(256) void k_gemmv(
    const u16* __restrict__ A, int lda, const u16* __restrict__ Bt,
    const float* __restrict__ bias, const float* __restrict__ wbuf, int kp,
    float* __restrict__ ctxf, u16* __restrict__ ctxO, int K)
{
  __shared__ alignas(16) u16 As[128 * 32];
  __shared__ alignas(16) u16 Bs[128 * 32];
  f32x4 acc[4][4] = {};
  gemm_main(A, lda, Bt, K, As, Bs, acc);
  const int ln = threadIdx.x & 63;
  const int w = threadIdx.x >> 6;
  const int wm = w >> 1, wn = w & 1;
  const int m0 = blockIdx.x * 128, n0 = blockIdx.y * 128;
#pragma unroll
  for (int n = 0; n < 4; ++n) {
    const int gc = n0 + wn * 64 + n * 16 + (ln & 15);
    const float bv = bias[gc];
    const int h = gc >> 6;
#pragma unroll
    for (int m = 0; m < 4; ++m) {
#pragma unroll
      for (int j = 0; j < 4; ++j) {
        const int gr = m0 + wm * 64 + m * 16 + (ln >> 4) * 4 + j;
        const float ws = wbuf[((size_t)gr * 8 + h) * 4 + kp];
        float v = (acc[m][n][j] + bv) * ws;
        if constexpr (MODE > 0) v += ctxf[(size_t)gr * DM + gc];
        if constexpr (MODE == 2) ctxO[(size_t)gr * DM + gc] = f2bf(v);
        else                     ctxf[(size_t)gr * DM + gc] = v;
      }
    }
  }
}

// raw score for one key position: wbuf[b][h][kp] = (q . k)/8, wave per token
__global__ __launch_bounds__(256) void k_dotp(
    const u16* __restrict__ Q, const u16* __restrict__ Kt,
    float* __restrict__ wbuf, int kp)
{
  const int ln = threadIdx.x & 63;
  const int b  = blockIdx.x * 4 + (threadIdx.x >> 6);
  float q[8], k[8];
  { uint4 t = ((const uint4*)(Q  + (size_t)b * DM))[ln]; unpack8(t, q); }
  { uint4 t = ((const uint4*)(Kt + (size_t)b * DM))[ln]; unpack8(t, k); }
  float d = 0.f;
#pragma unroll
  for (int j = 0; j < 8; ++j) d += q[j] * k[j];
  d += __shfl_xor(d, 1, 64);
  d += __shfl_xor(d, 2, 64);
  d += __shfl_xor(d, 4, 64);
  if ((ln & 7) == 0) wbuf[((size_t)b * 8 + (ln >> 3)) * 4 + kp] = d * 0.125f;
}

// softmax over kp in-place on wbuf [B][H][4]; optional copy to attn0 [B][S][H][4]
__global__ __launch_bounds__(256) void k_softmax(
    float* __restrict__ wbuf, float* __restrict__ a0, int s)
{
  const int t = blockIdx.x * 256 + threadIdx.x;   // (b*8 + h)
  float4 v = ((const float4*)wbuf)[t];
  const float mx = fmaxf(fmaxf(v.x, v.y), fmaxf(v.z, v.w));
  float4 e;
  e.x = __expf(v.x - mx); e.y = __expf(v.y - mx);
  e.z = __expf(v.z - mx); e.w = __expf(v.w - mx);
  const float inv = 1.f / (e.x + e.y + e.z + e.w);
  e.x *= inv; e.y *= inv; e.z *= inv; e.w *= inv;
  ((float4*)wbuf)[t] = e;
  if (a0 != nullptr) {
    const int b = t >> 3, h = t & 7;
    ((float4*)a0)[((size_t)b * NS + s) * 8 + h] = e;
  }
}

// in-place LayerNorm over each 512-wide stream block of xcat; wave per (b,s)
__global__ __launch_bounds__(256) void k_ln(
    u16* __restrict__ xcat, const float* __restrict__ g, const float* __restrict__ bb)
{
  const int ln = threadIdx.x & 63;
  const int row = blockIdx.x * 4 + (threadIdx.x >> 6);
  const int b = row >> 2, s = row & 3;
  u16* p = xcat + (size_t)b * XW + s * DM;
  float v[8];
  { uint4 t = ((const uint4*)p)[ln]; unpack8(t, v); }
  float sum = 0.f;
#pragma unroll
  for (int j = 0; j < 8; ++j) sum += v[j];
#pragma unroll
  for (int off = 1; off < 64; off <<= 1) sum += __shfl_xor(sum, off, 64);
  const float mu = sum * (1.f / DM);
  float s2 = 0.f;
#pragma unroll
  for (int j = 0; j < 8; ++j) { float d = v[j] - mu; s2 += d * d; }
#pragma unroll
  for (int off = 1; off < 64; off <<= 1) s2 += __shfl_xor(s2, off, 64);
  const float rs = rsqrtf(s2 * (1.f / DM) + EPSL);
  const int e0 = s * DM + ln * 8;
  float o[8];
#pragma unroll
  for (int j = 0; j < 8; ++j) o[j] = (v[j] - mu) * rs * g[e0 + j] + bb[e0 + j];
  ((uint4*)p)[ln] = pack8(o);
}

// pack 4 fp32 streams -> xcat bf16 [B][S*D]
__global__ void k_pack(const float* __restrict__ t0, const float* __restrict__ t1,
                       const float* __restrict__ t2, const float* __restrict__ t3,
                       u16* __restrict__ xcat)
{
  const int total = NB * XW / 8;
  for (int t = blockIdx.x * blockDim.x + threadIdx.x; t < total; t += gridDim.x * blockDim.x) {
    const int b = t >> 8;
    const int r = t & 255;
    const int s = r >> 6;
    const int d0 = (r & 63) * 8;
    const float* p = (s == 0) ? t0 : (s == 1) ? t1 : (s == 2) ? t2 : t3;
    float f[8];
#pragma unroll
    for (int j = 0; j < 8; ++j) f[j] = p[(size_t)b * DM + d0 + j];
    ((uint4*)xcat)[t] = pack8(f);
  }
}

// transpose + fp32->bf16: src nb x [R][C] -> dst nb x [C][R]; R,C are pow2 (pass logs)
__global__ void k_tcvt(const float* __restrict__ src, u16* __restrict__ dst,
                       int rlog, int clog, int nb)
{
  const int mlog = rlog + clog;
  const size_t total = (size_t)nb << mlog;
  for (size_t t = (size_t)blockIdx.x * blockDim.x + threadIdx.x; t < total;
       t += (size_t)gridDim.x * blockDim.x) {
    const size_t mat = t >> mlog;
    const uint32_t rem = (uint32_t)(t & ((1u << mlog) - 1));
    const uint32_t n = rem >> rlog;
    const uint32_t r = rem & ((1u << rlog) - 1);
    dst[t] = f2bf(src[(mat << mlog) + ((size_t)r << clog) + n]);
  }
}

extern "C" void kernel_launch(void* const* d_in, const int* in_sizes, int n_in,
                              void* d_out, int out_size, void* d_ws, size_t ws_size,
                              hipStream_t stream)
{
  (void)in_sizes; (void)n_in; (void)out_size;
  const float* t0  = (const float*)d_in[0];
  const float* t1  = (const float*)d_in[1];
  const float* t2  = (const float*)d_in[2];
  const float* t3  = (const float*)d_in[3];
  const float* Wq  = (const float*)d_in[4];
  const float* bq  = (const float*)d_in[5];
  const float* Wk  = (const float*)d_in[6];
  const float* bk  = (const float*)d_in[7];
  const float* Wv  = (const float*)d_in[8];
  const float* bv  = (const float*)d_in[9];
  const float* Wo  = (const float*)d_in[10];
  const float* bo  = (const float*)d_in[11];
  const float* lng = (const float*)d_in[12];
  const float* lnb = (const float*)d_in[13];
  const float* W1  = (const float*)d_in[14];
  const float* b1  = (const float*)d_in[15];
  const float* W2  = (const float*)d_in[16];
  const float* b2  = (const float*)d_in[17];
  const float* Wf1 = (const float*)d_in[18];
  const float* bf1 = (const float*)d_in[19];
  const float* Wf2 = (const float*)d_in[20];
  const float* bf2 = (const float*)d_in[21];

  size_t off = 0;
  char* ws = (char*)d_ws;
  auto take = [&](size_t n) { char* p = ws + off; off += (n + 255) & ~(size_t)255; return p; };
  u16* WqT  = (u16*)take(8ull * DM * DM * 2);        //  4 MiB
  u16* WkT  = (u16*)take(8ull * DM * DM * 2);        //  4
  u16* WvT  = (u16*)take(8ull * DM * DM * 2);        //  4
  u16* WoT  = (u16*)take(8ull * DM * DM * 2);        //  4
  u16* W1T  = (u16*)take(8ull * DM * FH * 2);        // 16
  u16* W2T  = (u16*)take(8ull * FH * DM * 2);        // 16
  u16* Wf1T = (u16*)take((size_t)XW * 1024 * 2);     //  4
  u16* Wf2T = (u16*)take((size_t)1024 * DM * 2);     //  1
  u16* xcat = (u16*)take((size_t)NB * XW * 2);       // 64
  char* rgA = take((size_t)NB * DM * 4);             // 32: {Qb,Ktmp} | ctxf
  float* wbuf = (float*)take((size_t)NB * 8 * 4 * 4);//  2
  char* rgR = take(4ull * NB * DM * 2);              // 64: ctxb[4] | ffn1 | y1
  const size_t needed = off;                          // ~215 MiB

  u16* Qb   = (u16*)rgA;
  u16* Ktmp = (u16*)(rgA + (size_t)NB * DM * 2);
  float* ctxf = (float*)rgA;
  u16* ctxb = (u16*)rgR;
  u16* ffn1 = (u16*)rgR;
  u16* y1   = (u16*)rgR;
  float* attn0 = (float*)d_out + (size_t)NB * DM;

  if (needed > ws_size) return;  // diagnostic: clean absmax-fail instead of GPU fault

  // weight prep: fp32 -> bf16, transposed to [N][K]
  k_tcvt<<<dim3(1024), dim3(256), 0, stream>>>(Wq, WqT, 9, 9, 8);
  k_tcvt<<<dim3(1024), dim3(256), 0, stream>>>(Wk, WkT, 9, 9, 8);
  k_tcvt<<<dim3(1024), dim3(256), 0, stream>>>(Wv, WvT, 9, 9, 8);
  k_tcvt<<<dim3(1024), dim3(256), 0, stream>>>(Wo, WoT, 9, 9, 8);
  k_tcvt<<<dim3(1024), dim3(256), 0, stream>>>(W1, W1T, 9, 11, 8);
  k_tcvt<<<dim3(1024), dim3(256), 0, stream>>>(W2, W2T, 11, 9, 8);
  k_tcvt<<<dim3(1024), dim3(256), 0, stream>>>(Wf1, Wf1T, 11, 10, 1);
  k_tcvt<<<dim3(1024), dim3(256), 0, stream>>>(Wf2, Wf2T, 10, 9, 1);
  k_pack<<<dim3(2048), dim3(256), 0, stream>>>(t0, t1, t2, t3, xcat);

  const size_t WSQ = (size_t)DM * DM;
  for (int ly = 0; ly < 2; ++ly) {
    for (int s = 0; s < NS; ++s) {
      const size_t wsl = (size_t)(ly * 4 + s);
      // Q projection of stream s's own token
      k_gemm<false, false, false><<<dim3(128, 4), dim3(256), 0, stream>>>(
          xcat + s * DM, XW, WqT + wsl * WSQ, bq + wsl * DM, nullptr, 0, Qb, DM, DM);
      // K per key position (streamed) + raw scores
      for (int kp = 0; kp < 4; ++kp) {
        k_gemm<false, false, false><<<dim3(128, 4), dim3(256), 0, stream>>>(
            xcat + kp * DM, XW, WkT + wsl * WSQ, bk + wsl * DM, nullptr, 0, Ktmp, DM, DM);
        k_dotp<<<dim3(NB / 4), dim3(256), 0, stream>>>(Qb, Ktmp, wbuf, kp);
      }
      k_softmax<<<dim3(NB * 8 / 256), dim3(256), 0, stream>>>(
          wbuf, (ly == 0) ? attn0 : (float*)nullptr, s);
      // V per key position, weighted-accumulated into ctx (fp32), last writes bf16
      for (int kp = 0; kp < 4; ++kp) {
        if (kp == 0)
          k_gemmv<0><<<dim3(128, 4), dim3(256), 0, stream>>>(
              xcat + kp * DM, XW, WvT + wsl * WSQ, bv + wsl * DM, wbuf, kp, ctxf, nullptr, DM);
        else if (kp < 3)
          k_gemmv<1><<<dim3(128, 4), dim3(256), 0, stream>>>(
              xcat + kp * DM, XW, WvT + wsl * WSQ, bv + wsl * DM, wbuf, kp, ctxf, nullptr, DM);
        else
          k_gemmv<2><<<dim3(128, 4), dim3(256), 0, stream>>>(
              xcat + kp * DM, XW, WvT + wsl * WSQ, bv + wsl * DM, wbuf, kp, ctxf,
              ctxb + (size_t)s * NB * DM, DM);
      }
    }
    // O projection, residual-fused, in-place into xcat
    for (int s = 0; s < NS; ++s) {
      const size_t wsl = (size_t)(ly * 4 + s);
      k_gemm<false, true, false><<<dim3(128, 4), dim3(256), 0, stream>>>(
          ctxb + (size_t)s * NB * DM, DM, WoT + wsl * WSQ, bo + wsl * DM,
          xcat + s * DM, XW, xcat + s * DM, XW, DM);
    }
    k_ln<<<dim3(NB), dim3(256), 0, stream>>>(xcat, lng + ly * XW, lnb + ly * XW);
    // FFN, residual-fused, in-place into xcat
    for (int s = 0; s < NS; ++s) {
      const size_t wsl = (size_t)(ly * 4 + s);
      k_gemm<true, false, false><<<dim3(128, 16), dim3(256), 0, stream>>>(
          xcat + s * DM, XW, W1T + wsl * (size_t)DM * FH, b1 + wsl * FH,
          nullptr, 0, ffn1, FH, DM);
      k_gemm<false, true, false><<<dim3(128, 4), dim3(256), 0, stream>>>(
          ffn1, FH, W2T + wsl * (size_t)FH * DM, b2 + wsl * DM,
          xcat + s * DM, XW, xcat + s * DM, XW, FH);
    }
  }
  // final fusion MLP
  k_gemm<true, false, false><<<dim3(128, 8), dim3(256), 0, stream>>>(
      xcat, XW, Wf1T, bf1, nullptr, 0, y1, 1024, XW);
  k_gemm<false, false, true><<<dim3(128, 4), dim3(256), 0, stream>>>(
      y1, 1024, Wf2T, bf2, nullptr, 0, d_out, DM, 1024);
}

// Round 3
// 3061.232 us; speedup vs baseline: 1.2390x; 1.2390x over previous
//
#include <hip/hip_runtime.h>
#include <stdint.h>

typedef unsigned short u16;
typedef __bf16 bf16x8 __attribute__((ext_vector_type(8)));
typedef float f32x4 __attribute__((ext_vector_type(4)));

constexpr int NB = 16384;        // batch tokens
constexpr int DM = 512;          // model dim
constexpr int NS = 4;            // streams
constexpr int FH = 2048;         // FFN hidden
constexpr int XW = NS * DM;      // 2048 concat width
constexpr float EPSL = 1e-5f;

__device__ __forceinline__ float bf2f(u16 u) { return __uint_as_float(((uint32_t)u) << 16); }
__device__ __forceinline__ u16 f2bf(float f) {
  uint32_t u = __float_as_uint(f);
  u += 0x7fffu + ((u >> 16) & 1u);
  return (u16)(u >> 16);
}
__device__ __forceinline__ void unpack8(uint4 p, float* f) {
  f[0] = __uint_as_float(p.x << 16); f[1] = __uint_as_float(p.x & 0xffff0000u);
  f[2] = __uint_as_float(p.y << 16); f[3] = __uint_as_float(p.y & 0xffff0000u);
  f[4] = __uint_as_float(p.z << 16); f[5] = __uint_as_float(p.z & 0xffff0000u);
  f[6] = __uint_as_float(p.w << 16); f[7] = __uint_as_float(p.w & 0xffff0000u);
}
__device__ __forceinline__ uint4 pack8(const float* f) {
  uint4 r;
  r.x = (uint32_t)f2bf(f[0]) | ((uint32_t)f2bf(f[1]) << 16);
  r.y = (uint32_t)f2bf(f[2]) | ((uint32_t)f2bf(f[3]) << 16);
  r.z = (uint32_t)f2bf(f[4]) | ((uint32_t)f2bf(f[5]) << 16);
  r.w = (uint32_t)f2bf(f[6]) | ((uint32_t)f2bf(f[7]) << 16);
  return r;
}
__device__ __forceinline__ void gl_lds16(const void* g, void* l) {
  __builtin_amdgcn_global_load_lds((const __attribute__((address_space(1))) void*)g,
                                   (__attribute__((address_space(3))) void*)l, 16, 0, 0);
}

// ---- double-buffered 2-phase GEMM main loop: 128x128 tile, BK=32, 256 threads ----
// prefetch K-tile t+1 issued BEFORE ds_read+MFMA of tile t; one barrier per K-step
__device__ __forceinline__ void gemm_main_db(
    const u16* __restrict__ A, int lda, const u16* __restrict__ Bt, int K,
    u16* As, u16* Bs, f32x4 (&acc)[4][4])
{
  const int tid = threadIdx.x;
  const int ln = tid & 63;
  const int w  = tid >> 6;
  const int wm = w >> 1, wn = w & 1;
  const int m0 = blockIdx.x * 128;
  const int n0 = blockIdx.y * 128;
  const int sr = ln >> 2;
  const int sc = (ln & 3) * 8;
  const u16* Ab = A  + (size_t)(m0 + w * 32 + sr) * lda + sc;
  const u16* Bb = Bt + (size_t)(n0 + w * 32 + sr) * K   + sc;

  auto stage = [&](int buf, int k0) {
#pragma unroll
    for (int i = 0; i < 2; ++i) {
      gl_lds16(Ab + (size_t)i * 16 * lda + k0, &As[buf * 4096 + (w * 32 + i * 16) * 32]);
      gl_lds16(Bb + (size_t)i * 16 * K   + k0, &Bs[buf * 4096 + (w * 32 + i * 16) * 32]);
    }
  };
  stage(0, 0);
  __syncthreads();   // includes vmcnt(0) drain
  const int nt = K >> 5;
  for (int t = 0; t < nt; ++t) {
    const int cur = t & 1;
    if (t + 1 < nt) stage(cur ^ 1, (t + 1) * 32);   // in flight under compute
    bf16x8 af[4], bfv[4];
#pragma unroll
    for (int m = 0; m < 4; ++m) {
      af[m]  = *(const bf16x8*)&As[cur * 4096 + (wm * 64 + m * 16 + (ln & 15)) * 32 + (ln >> 4) * 8];
      bfv[m] = *(const bf16x8*)&Bs[cur * 4096 + (wn * 64 + m * 16 + (ln & 15)) * 32 + (ln >> 4) * 8];
    }
#pragma unroll
    for (int m = 0; m < 4; ++m)
#pragma unroll
      for (int n = 0; n < 4; ++n)
        acc[m][n] = __builtin_amdgcn_mfma_f32_16x16x32_bf16(af[m], bfv[n], acc[m][n], 0, 0, 0);
    __syncthreads();
  }
}

// generic GEMM with per-z offsets: C = A*Bt^T + bias [+Rsd][ReLU]
template<bool RELU, bool RESID, bool OUTF32>
__global__ __launch_bounds__(256) void k_gemm(
    const u16* __restrict__ A, int lda, long aZ,
    const u16* __restrict__ Bt, long bZ,
    const float* __restrict__ bias, long biasZ,
    const u16* __restrict__ Rsd, int ldr, long rZ,
    void* __restrict__ Cp, int ldc, long cZ, int K)
{
  const int z = blockIdx.z;
  A += (long)z * aZ; Bt += (long)z * bZ; bias += (long)z * biasZ;
  __shared__ alignas(16) u16 As[2 * 4096];
  __shared__ alignas(16) u16 Bs[2 * 4096];
  f32x4 acc[4][4] = {};
  gemm_main_db(A, lda, Bt, K, As, Bs, acc);
  const int ln = threadIdx.x & 63;
  const int w = threadIdx.x >> 6;
  const int wm = w >> 1, wn = w & 1;
  const int m0 = blockIdx.x * 128, n0 = blockIdx.y * 128;
#pragma unroll
  for (int n = 0; n < 4; ++n) {
    const int gc = n0 + wn * 64 + n * 16 + (ln & 15);
    const float bv = bias[gc];
#pragma unroll
    for (int m = 0; m < 4; ++m) {
#pragma unroll
      for (int j = 0; j < 4; ++j) {
        const int gr = m0 + wm * 64 + m * 16 + (ln >> 4) * 4 + j;
        float v = acc[m][n][j] + bv;
        if constexpr (RESID) v += bf2f(Rsd[(long)z * rZ + (size_t)gr * ldr + gc]);
        if constexpr (RELU)  v = v > 0.f ? v : 0.f;
        if constexpr (OUTF32) ((float*)Cp)[(long)z * cZ + (size_t)gr * ldc + gc] = v;
        else                  ((u16*)Cp)[(long)z * cZ + (size_t)gr * ldc + gc] = f2bf(v);
      }
    }
  }
}

// K-projection GEMM with fused q.k dot epilogue.
// z = s*4+kp. Block tile [128 rows, 128 cols] covers exactly 2 whole heads.
// Writes raw scores (scaled by 1/8) to wbuf[s][b][h][kp]. K-bias dropped
// (constant across kp -> softmax-invariant).
__global__ __launch_bounds__(256) void k_kdot(
    const u16* __restrict__ xcat, const u16* __restrict__ WkT_l,
    const u16* __restrict__ Qb, float* __restrict__ wbuf)
{
  const int s = blockIdx.z >> 2, kp = blockIdx.z & 3;
  __shared__ alignas(16) u16 As[2 * 4096];
  __shared__ alignas(16) u16 Bs[2 * 4096];
  f32x4 acc[4][4] = {};
  gemm_main_db(xcat + kp * DM, XW, WkT_l + (size_t)s * DM * DM, DM, As, Bs, acc);
  const int ln = threadIdx.x & 63;
  const int w = threadIdx.x >> 6;
  const int wm = w >> 1, wn = w & 1;
  const int m0 = blockIdx.x * 128, n0 = blockIdx.y * 128;
  const int h = (n0 >> 6) + wn;
  float p[4][4];
#pragma unroll
  for (int m = 0; m < 4; ++m)
#pragma unroll
    for (int j = 0; j < 4; ++j) p[m][j] = 0.f;
#pragma unroll
  for (int n = 0; n < 4; ++n) {
    const int gc = n0 + wn * 64 + n * 16 + (ln & 15);
#pragma unroll
    for (int m = 0; m < 4; ++m) {
#pragma unroll
      for (int j = 0; j < 4; ++j) {
        const int gr = m0 + wm * 64 + m * 16 + (ln >> 4) * 4 + j;
        p[m][j] += acc[m][n][j] * bf2f(Qb[((size_t)s * NB + gr) * DM + gc]);
      }
    }
  }
#pragma unroll
  for (int m = 0; m < 4; ++m)
#pragma unroll
    for (int j = 0; j < 4; ++j) {
      float v = p[m][j];
      v += __shfl_xor(v, 1, 64);
      v += __shfl_xor(v, 2, 64);
      v += __shfl_xor(v, 4, 64);
      v += __shfl_xor(v, 8, 64);
      p[m][j] = v;
    }
  if ((ln & 15) == 0) {
#pragma unroll
    for (int m = 0; m < 4; ++m)
#pragma unroll
      for (int j = 0; j < 4; ++j) {
        const int gr = m0 + wm * 64 + m * 16 + (ln >> 4) * 4 + j;
        wbuf[(((size_t)s * NB + gr) * 8 + h) * 4 + kp] = p[m][j] * 0.125f;
      }
  }
}

// V-projection (all streams, N=2048) with fused softmax weighting, chained over kp:
// ctxc[b, s*512+e] (+)= w[s,b,h,kp] * ((x_kp Wv[s])_e + bv)
template<bool FIRST>
__global__ __launch_bounds__(256) void k_gemmv(
    const u16* __restrict__ Akp, const u16* __restrict__ WvT_l,
    const float* __restrict__ bv_l, const float* __restrict__ wbuf, int kp,
    u16* __restrict__ ctxc)
{
  __shared__ alignas(16) u16 As[2 * 4096];
  __shared__ alignas(16) u16 Bs[2 * 4096];
  f32x4 acc[4][4] = {};
  gemm_main_db(Akp, XW, WvT_l, DM, As, Bs, acc);
  const int ln = threadIdx.x & 63;
  const int w = threadIdx.x >> 6;
  const int wm = w >> 1, wn = w & 1;
  const int m0 = blockIdx.x * 128, n0 = blockIdx.y * 128;
#pragma unroll
  for (int n = 0; n < 4; ++n) {
    const int gc = n0 + wn * 64 + n * 16 + (ln & 15);
    const float bv = bv_l[gc];
    const int s = gc >> 9, h = (gc >> 6) & 7;
#pragma unroll
    for (int m = 0; m < 4; ++m) {
#pragma unroll
      for (int j = 0; j < 4; ++j) {
        const int gr = m0 + wm * 64 + m * 16 + (ln >> 4) * 4 + j;
        const float ws = wbuf[(((size_t)s * NB + gr) * 8 + h) * 4 + kp];
        float v = (acc[m][n][j] + bv) * ws;
        if constexpr (!FIRST) v += bf2f(ctxc[(size_t)gr * XW + gc]);
        ctxc[(size_t)gr * XW + gc] = f2bf(v);
      }
    }
  }
}

// softmax over kp in-place on wbuf [S][B][H][4]; optional write to attn0 [B][S][H][4]
__global__ __launch_bounds__(256) void k_softmax(
    float* __restrict__ wbuf, float* __restrict__ a0)
{
  const int t = blockIdx.x * 256 + threadIdx.x;   // (s*NB + b)*8 + h
  float4 v = ((const float4*)wbuf)[t];
  const float mx = fmaxf(fmaxf(v.x, v.y), fmaxf(v.z, v.w));
  float4 e;
  e.x = __expf(v.x - mx); e.y = __expf(v.y - mx);
  e.z = __expf(v.z - mx); e.w = __expf(v.w - mx);
  const float inv = 1.f / (e.x + e.y + e.z + e.w);
  e.x *= inv; e.y *= inv; e.z *= inv; e.w *= inv;
  ((float4*)wbuf)[t] = e;
  if (a0 != nullptr) {
    const int s = t >> 17, b = (t >> 3) & (NB - 1), h = t & 7;
    ((float4*)a0)[((size_t)b * NS + s) * 8 + h] = e;
  }
}

// in-place LayerNorm over each 512-wide stream block of xcat; wave per (b,s)
__global__ __launch_bounds__(256) void k_ln(
    u16* __restrict__ xcat, const float* __restrict__ g, const float* __restrict__ bb)
{
  const int ln = threadIdx.x & 63;
  const int row = blockIdx.x * 4 + (threadIdx.x >> 6);
  const int b = row >> 2, s = row & 3;
  u16* p = xcat + (size_t)b * XW + s * DM;
  float v[8];
  { uint4 t = ((const uint4*)p)[ln]; unpack8(t, v); }
  float sum = 0.f;
#pragma unroll
  for (int j = 0; j < 8; ++j) sum += v[j];
#pragma unroll
  for (int off = 1; off < 64; off <<= 1) sum += __shfl_xor(sum, off, 64);
  const float mu = sum * (1.f / DM);
  float s2 = 0.f;
#pragma unroll
  for (int j = 0; j < 8; ++j) { float d = v[j] - mu; s2 += d * d; }
#pragma unroll
  for (int off = 1; off < 64; off <<= 1) s2 += __shfl_xor(s2, off, 64);
  const float rs = rsqrtf(s2 * (1.f / DM) + EPSL);
  const int e0 = s * DM + ln * 8;
  float o[8];
#pragma unroll
  for (int j = 0; j < 8; ++j) o[j] = (v[j] - mu) * rs * g[e0 + j] + bb[e0 + j];
  ((uint4*)p)[ln] = pack8(o);
}

// pack 4 fp32 streams -> xcat bf16 [B][S*D]
__global__ void k_pack(const float* __restrict__ t0, const float* __restrict__ t1,
                       const float* __restrict__ t2, const float* __restrict__ t3,
                       u16* __restrict__ xcat)
{
  const int total = NB * XW / 8;
  for (int t = blockIdx.x * blockDim.x + threadIdx.x; t < total; t += gridDim.x * blockDim.x) {
    const int b = t >> 8;
    const int r = t & 255;
    const int s = r >> 6;
    const int d0 = (r & 63) * 8;
    const float* p = (s == 0) ? t0 : (s == 1) ? t1 : (s == 2) ? t2 : t3;
    float f[8];
#pragma unroll
    for (int j = 0; j < 8; ++j) f[j] = p[(size_t)b * DM + d0 + j];
    ((uint4*)xcat)[t] = pack8(f);
  }
}

// transpose + fp32->bf16: src nb x [R][C] -> dst nb x [C][R]; pow2 dims (pass logs)
__global__ void k_tcvt(const float* __restrict__ src, u16* __restrict__ dst,
                       int rlog, int clog, int nb)
{
  const int mlog = rlog + clog;
  const size_t total = (size_t)nb << mlog;
  for (size_t t = (size_t)blockIdx.x * blockDim.x + threadIdx.x; t < total;
       t += (size_t)gridDim.x * blockDim.x) {
    const size_t mat = t >> mlog;
    const uint32_t rem = (uint32_t)(t & ((1u << mlog) - 1));
    const uint32_t n = rem >> rlog;
    const uint32_t r = rem & ((1u << rlog) - 1);
    dst[t] = f2bf(src[(mat << mlog) + ((size_t)r << clog) + n]);
  }
}

extern "C" void kernel_launch(void* const* d_in, const int* in_sizes, int n_in,
                              void* d_out, int out_size, void* d_ws, size_t ws_size,
                              hipStream_t stream)
{
  (void)in_sizes; (void)n_in; (void)out_size;
  const float* t0  = (const float*)d_in[0];
  const float* t1  = (const float*)d_in[1];
  const float* t2  = (const float*)d_in[2];
  const float* t3  = (const float*)d_in[3];
  const float* Wq  = (const float*)d_in[4];
  const float* bq  = (const float*)d_in[5];
  const float* Wk  = (const float*)d_in[6];
  const float* Wv  = (const float*)d_in[8];
  const float* bv  = (const float*)d_in[9];
  const float* Wo  = (const float*)d_in[10];
  const float* bo  = (const float*)d_in[11];
  const float* lng = (const float*)d_in[12];
  const float* lnb = (const float*)d_in[13];
  const float* W1  = (const float*)d_in[14];
  const float* b1  = (const float*)d_in[15];
  const float* W2  = (const float*)d_in[16];
  const float* b2  = (const float*)d_in[17];
  const float* Wf1 = (const float*)d_in[18];
  const float* bf1 = (const float*)d_in[19];
  const float* Wf2 = (const float*)d_in[20];
  const float* bf2 = (const float*)d_in[21];

  size_t off = 0;
  char* ws = (char*)d_ws;
  auto take = [&](size_t n) { char* p = ws + off; off += (n + 255) & ~(size_t)255; return p; };
  u16* WqT  = (u16*)take(8ull * DM * DM * 2);        //  4 MiB
  u16* WkT  = (u16*)take(8ull * DM * DM * 2);        //  4
  u16* WvT  = (u16*)take(8ull * DM * DM * 2);        //  4
  u16* WoT  = (u16*)take(8ull * DM * DM * 2);        //  4
  u16* W1T  = (u16*)take(8ull * DM * FH * 2);        // 16
  u16* W2T  = (u16*)take(8ull * FH * DM * 2);        // 16
  u16* Wf1T = (u16*)take((size_t)XW * 1024 * 2);     //  4
  u16* Wf2T = (u16*)take((size_t)1024 * DM * 2);     //  1
  u16* xcat = (u16*)take((size_t)NB * XW * 2);       // 64
  char* U1  = take((size_t)NB * XW * 2);             // 64: Qb | ctxc | ffn1 | y1
  float* wbuf = (float*)take(4ull * NB * 8 * 4 * 4); //  8
  const size_t needed = off;                          // ~189 MiB

  u16* Qb   = (u16*)U1;   // [S][B][512]
  u16* ctxc = (u16*)U1;   // [B][2048]
  u16* ffn1 = (u16*)U1;   // [B][2048] per stream
  u16* y1   = (u16*)U1;   // [B][1024]
  float* attn0 = (float*)d_out + (size_t)NB * DM;

  if (needed > ws_size) return;  // diagnostic: clean fail instead of GPU fault

  // weight prep: fp32 -> bf16, transposed to [N][K]
  k_tcvt<<<dim3(1024), dim3(256), 0, stream>>>(Wq, WqT, 9, 9, 8);
  k_tcvt<<<dim3(1024), dim3(256), 0, stream>>>(Wk, WkT, 9, 9, 8);
  k_tcvt<<<dim3(1024), dim3(256), 0, stream>>>(Wv, WvT, 9, 9, 8);
  k_tcvt<<<dim3(1024), dim3(256), 0, stream>>>(Wo, WoT, 9, 9, 8);
  k_tcvt<<<dim3(1024), dim3(256), 0, stream>>>(W1, W1T, 9, 11, 8);
  k_tcvt<<<dim3(1024), dim3(256), 0, stream>>>(W2, W2T, 11, 9, 8);
  k_tcvt<<<dim3(1024), dim3(256), 0, stream>>>(Wf1, Wf1T, 11, 10, 1);
  k_tcvt<<<dim3(1024), dim3(256), 0, stream>>>(Wf2, Wf2T, 10, 9, 1);
  k_pack<<<dim3(2048), dim3(256), 0, stream>>>(t0, t1, t2, t3, xcat);

  const size_t WSQ = (size_t)DM * DM;
  for (int ly = 0; ly < 2; ++ly) {
    const u16* WqT_l = WqT + (size_t)ly * 4 * WSQ;
    const u16* WkT_l = WkT + (size_t)ly * 4 * WSQ;
    const u16* WvT_l = WvT + (size_t)ly * 4 * WSQ;
    const u16* WoT_l = WoT + (size_t)ly * 4 * WSQ;
    // Q projection, all streams in one launch (z = s)
    k_gemm<false, false, false><<<dim3(128, 4, 4), dim3(256), 0, stream>>>(
        xcat, XW, DM, WqT_l, WSQ, bq + (size_t)ly * XW, DM,
        nullptr, 0, 0, Qb, DM, (long)NB * DM, DM);
    // K projection + fused q.k dot, all (s,kp) in one launch
    k_kdot<<<dim3(128, 4, 16), dim3(256), 0, stream>>>(xcat, WkT_l, Qb, wbuf);
    k_softmax<<<dim3(4 * NB * 8 / 256), dim3(256), 0, stream>>>(
        wbuf, (ly == 0) ? attn0 : (float*)nullptr);
    // V projection (N=2048 over streams), weighted, chained over kp
    k_gemmv<true><<<dim3(128, 16), dim3(256), 0, stream>>>(
        xcat + 0 * DM, WvT_l, bv + (size_t)ly * XW, wbuf, 0, ctxc);
    for (int kp = 1; kp < 4; ++kp)
      k_gemmv<false><<<dim3(128, 16), dim3(256), 0, stream>>>(
          xcat + kp * DM, WvT_l, bv + (size_t)ly * XW, wbuf, kp, ctxc);
    // O projection, residual-fused, in-place into xcat (z = s)
    k_gemm<false, true, false><<<dim3(128, 4, 4), dim3(256), 0, stream>>>(
        ctxc, XW, DM, WoT_l, WSQ, bo + (size_t)ly * XW, DM,
        xcat, XW, DM, xcat, XW, DM, DM);
    k_ln<<<dim3(NB), dim3(256), 0, stream>>>(xcat, lng + ly * XW, lnb + ly * XW);
    // FFN per stream, residual-fused, in-place into xcat
    for (int s = 0; s < NS; ++s) {
      const size_t wsl = (size_t)(ly * 4 + s);
      k_gemm<true, false, false><<<dim3(128, 16, 1), dim3(256), 0, stream>>>(
          xcat + s * DM, XW, 0, W1T + wsl * (size_t)DM * FH, 0, b1 + wsl * FH, 0,
          nullptr, 0, 0, ffn1, FH, 0, DM);
      k_gemm<false, true, false><<<dim3(128, 4, 1), dim3(256), 0, stream>>>(
          ffn1, FH, 0, W2T + wsl * (size_t)FH * DM, 0, b2 + wsl * DM, 0,
          xcat + s * DM, XW, 0, xcat + s * DM, XW, 0, FH);
    }
  }
  // final fusion MLP
  k_gemm<true, false, false><<<dim3(128, 8, 1), dim3(256), 0, stream>>>(
      xcat, XW, 0, Wf1T, 0, bf1, 0, nullptr, 0, 0, y1, 1024, 0, XW);
  k_gemm<false, false, true><<<dim3(128, 4, 1), dim3(256), 0, stream>>>(
      y1, 1024, 0, Wf2T, 0, bf2, 0, nullptr, 0, 0, d_out, DM, 0, 1024);
}

// Round 4
// 2699.787 us; speedup vs baseline: 1.4049x; 1.1339x over previous
//
#include <hip/hip_runtime.h>
#include <stdint.h>

typedef unsigned short u16;
typedef __bf16 bf16x8 __attribute__((ext_vector_type(8)));
typedef float f32x4 __attribute__((ext_vector_type(4)));

constexpr int NB = 16384;        // batch tokens
constexpr int DM = 512;          // model dim
constexpr int NS = 4;            // streams
constexpr int FH = 2048;         // FFN hidden
constexpr int XW = NS * DM;      // 2048 concat width
constexpr float EPSL = 1e-5f;

__device__ __forceinline__ float bf2f(u16 u) { return __uint_as_float(((uint32_t)u) << 16); }
__device__ __forceinline__ u16 f2bf(float f) {
  uint32_t u = __float_as_uint(f);
  u += 0x7fffu + ((u >> 16) & 1u);
  return (u16)(u >> 16);
}
__device__ __forceinline__ void unpack8(uint4 p, float* f) {
  f[0] = __uint_as_float(p.x << 16); f[1] = __uint_as_float(p.x & 0xffff0000u);
  f[2] = __uint_as_float(p.y << 16); f[3] = __uint_as_float(p.y & 0xffff0000u);
  f[4] = __uint_as_float(p.z << 16); f[5] = __uint_as_float(p.z & 0xffff0000u);
  f[6] = __uint_as_float(p.w << 16); f[7] = __uint_as_float(p.w & 0xffff0000u);
}
__device__ __forceinline__ uint4 pack8(const float* f) {
  uint4 r;
  r.x = (uint32_t)f2bf(f[0]) | ((uint32_t)f2bf(f[1]) << 16);
  r.y = (uint32_t)f2bf(f[2]) | ((uint32_t)f2bf(f[3]) << 16);
  r.z = (uint32_t)f2bf(f[4]) | ((uint32_t)f2bf(f[5]) << 16);
  r.w = (uint32_t)f2bf(f[6]) | ((uint32_t)f2bf(f[7]) << 16);
  return r;
}
__device__ __forceinline__ void gl_lds16(const void* g, void* l) {
  __builtin_amdgcn_global_load_lds((const __attribute__((address_space(1))) void*)g,
                                   (__attribute__((address_space(3))) void*)l, 16, 0, 0);
}

// ---- counted-vmcnt 3-buffer GEMM core: 128x128 tile, BK=32, 256 threads ----
// LDS swizzle (T2-lite): LDS stays write-linear for global_load_lds; the GLOBAL
// source 16B-block is pre-permuted blk^=(row>>1)&3 (per-quad coalescing kept),
// reads apply the same XOR -> even bank spread (2-way, free).
// Pipeline (T4): stage tile t+2 during compute of t; vmcnt(4) + raw s_barrier;
// loop body contains no other vmem so the count is exact. Outstanding=0 at exit.
__device__ __forceinline__ void gemm_cv(
    const u16* __restrict__ A, int lda,
    const u16* __restrict__ Bt, int K,    // Bt row stride == K
    u16* As, u16* Bs, f32x4 (&acc)[4][4])
{
  const int tid = threadIdx.x;
  const int ln = tid & 63;
  const int w  = tid >> 6;
  const int wm = w >> 1, wn = w & 1;
  const int m0 = blockIdx.x * 128;
  const int n0 = blockIdx.y * 128;
  const int grow = ln >> 2;                                  // row within 16-chunk
  const int gcol = ((ln & 3) ^ ((ln >> 3) & 3)) * 8;         // swizzled src 16B-block
  const u16* Ab = A  + (size_t)(m0 + w * 32 + grow) * lda + gcol;
  const u16* Bb = Bt + (size_t)(n0 + w * 32 + grow) * K   + gcol;

  auto stage = [&](int buf, int k0) {
#pragma unroll
    for (int i = 0; i < 2; ++i) {
      gl_lds16(Ab + (size_t)i * 16 * lda + k0, &As[buf * 4096 + (w * 32 + i * 16) * 32]);
      gl_lds16(Bb + (size_t)i * 16 * K   + k0, &Bs[buf * 4096 + (w * 32 + i * 16) * 32]);
    }
  };

  __syncthreads();               // protect LDS reuse across successive calls
  const int nt = K >> 5;
  stage(0, 0);
  if (nt > 1) {
    stage(1, 32);
    asm volatile("s_waitcnt vmcnt(4)" ::: "memory");
  } else {
    asm volatile("s_waitcnt vmcnt(0)" ::: "memory");
  }
  __builtin_amdgcn_s_barrier();
  asm volatile("" ::: "memory");

  const int rx = ((ln & 15) >> 1) & 3;   // per-row read XOR
  const int qb = ln >> 4;
  const int cb = (qb ^ rx) * 8;          // swizzled read 16B-block (elems)
  int cur = 0, nxt2 = 2;
  for (int t = 0; t < nt; ++t) {
    bf16x8 af[4], bfv[4];
#pragma unroll
    for (int m = 0; m < 4; ++m) {
      af[m]  = *(const bf16x8*)&As[cur * 4096 + (wm * 64 + m * 16 + (ln & 15)) * 32 + cb];
      bfv[m] = *(const bf16x8*)&Bs[cur * 4096 + (wn * 64 + m * 16 + (ln & 15)) * 32 + cb];
    }
#pragma unroll
    for (int m = 0; m < 4; ++m)
#pragma unroll
      for (int n = 0; n < 4; ++n)
        acc[m][n] = __builtin_amdgcn_mfma_f32_16x16x32_bf16(af[m], bfv[n], acc[m][n], 0, 0, 0);
    if (t + 2 < nt) {
      stage(nxt2, (t + 2) * 32);
      asm volatile("s_waitcnt vmcnt(4)" ::: "memory");   // tile t+1 ready, t+2 in flight
      __builtin_amdgcn_s_barrier();
      asm volatile("" ::: "memory");
    } else if (t + 1 < nt) {
      asm volatile("s_waitcnt vmcnt(0)" ::: "memory");   // drain last tile
      __builtin_amdgcn_s_barrier();
      asm volatile("" ::: "memory");
    }
    cur = cur + 1;  if (cur == 3)  cur = 0;
    nxt2 = nxt2 + 1; if (nxt2 == 3) nxt2 = 0;
  }
  asm volatile("" ::: "memory");   // fence: epilogue vmem must not hoist into loop
}

// generic GEMM with per-z offsets: C = A*Bt^T + bias [+Rsd][ReLU]
template<bool RELU, bool RESID, bool OUTF32>
__global__ __launch_bounds__(256) void k_gemm(
    const u16* __restrict__ A, int lda, long aZ,
    const u16* __restrict__ Bt, long bZ,
    const float* __restrict__ bias, long biasZ,
    const u16* __restrict__ Rsd, int ldr, long rZ,
    void* __restrict__ Cp, int ldc, long cZ, int K)
{
  const int z = blockIdx.z;
  A += (long)z * aZ; Bt += (long)z * bZ; bias += (long)z * biasZ;
  __shared__ alignas(16) u16 As[3 * 4096];
  __shared__ alignas(16) u16 Bs[3 * 4096];
  f32x4 acc[4][4] = {};
  gemm_cv(A, lda, Bt, K, As, Bs, acc);
  const int ln = threadIdx.x & 63;
  const int w = threadIdx.x >> 6;
  const int wm = w >> 1, wn = w & 1;
  const int m0 = blockIdx.x * 128, n0 = blockIdx.y * 128;
#pragma unroll
  for (int n = 0; n < 4; ++n) {
    const int gc = n0 + wn * 64 + n * 16 + (ln & 15);
    const float bv = bias[gc];
#pragma unroll
    for (int m = 0; m < 4; ++m) {
#pragma unroll
      for (int j = 0; j < 4; ++j) {
        const int gr = m0 + wm * 64 + m * 16 + (ln >> 4) * 4 + j;
        float v = acc[m][n][j] + bv;
        if constexpr (RESID) v += bf2f(Rsd[(long)z * rZ + (size_t)gr * ldr + gc]);
        if constexpr (RELU)  v = v > 0.f ? v : 0.f;
        if constexpr (OUTF32) ((float*)Cp)[(long)z * cZ + (size_t)gr * ldc + gc] = v;
        else                  ((u16*)Cp)[(long)z * cZ + (size_t)gr * ldc + gc] = f2bf(v);
      }
    }
  }
}

// K-projection GEMM with fused q.k dot epilogue. z = s*4+kp.
// Writes raw scores (x1/8) to wbuf[s][b][h][kp]. K-bias softmax-invariant, dropped.
__global__ __launch_bounds__(256) void k_kdot(
    const u16* __restrict__ xcat, const u16* __restrict__ WkT_l,
    const u16* __restrict__ Qb, float* __restrict__ wbuf)
{
  const int s = blockIdx.z >> 2, kp = blockIdx.z & 3;
  __shared__ alignas(16) u16 As[3 * 4096];
  __shared__ alignas(16) u16 Bs[3 * 4096];
  f32x4 acc[4][4] = {};
  gemm_cv(xcat + kp * DM, XW, WkT_l + (size_t)s * DM * DM, DM, As, Bs, acc);
  const int ln = threadIdx.x & 63;
  const int w = threadIdx.x >> 6;
  const int wm = w >> 1, wn = w & 1;
  const int m0 = blockIdx.x * 128, n0 = blockIdx.y * 128;
  const int h = (n0 >> 6) + wn;
  float p[4][4];
#pragma unroll
  for (int m = 0; m < 4; ++m)
#pragma unroll
    for (int j = 0; j < 4; ++j) p[m][j] = 0.f;
#pragma unroll
  for (int n = 0; n < 4; ++n) {
    const int gc = n0 + wn * 64 + n * 16 + (ln & 15);
#pragma unroll
    for (int m = 0; m < 4; ++m) {
#pragma unroll
      for (int j = 0; j < 4; ++j) {
        const int gr = m0 + wm * 64 + m * 16 + (ln >> 4) * 4 + j;
        p[m][j] += acc[m][n][j] * bf2f(Qb[((size_t)s * NB + gr) * DM + gc]);
      }
    }
  }
#pragma unroll
  for (int m = 0; m < 4; ++m)
#pragma unroll
    for (int j = 0; j < 4; ++j) {
      float v = p[m][j];
      v += __shfl_xor(v, 1, 64);
      v += __shfl_xor(v, 2, 64);
      v += __shfl_xor(v, 4, 64);
      v += __shfl_xor(v, 8, 64);
      p[m][j] = v;
    }
  if ((ln & 15) == 0) {
#pragma unroll
    for (int m = 0; m < 4; ++m)
#pragma unroll
      for (int j = 0; j < 4; ++j) {
        const int gr = m0 + wm * 64 + m * 16 + (ln >> 4) * 4 + j;
        wbuf[(((size_t)s * NB + gr) * 8 + h) * 4 + kp] = p[m][j] * 0.125f;
      }
  }
}

// V-projection for all 4 key positions fused: facc = sum_kp w[s,b,h,kp]*((x_kp Wv)_gc + bv)
// single bf16 write of ctxc [B][2048]; softmax weights read between phases (vmem-clean).
__global__ __launch_bounds__(256) void k_gemmv4(
    const u16* __restrict__ xcat, const u16* __restrict__ WvT_l,
    const float* __restrict__ bv_l, const float* __restrict__ wbuf,
    u16* __restrict__ ctxc)
{
  __shared__ alignas(16) u16 As[3 * 4096];
  __shared__ alignas(16) u16 Bs[3 * 4096];
  const int ln = threadIdx.x & 63;
  const int w = threadIdx.x >> 6;
  const int wm = w >> 1, wn = w & 1;
  const int m0 = blockIdx.x * 128, n0 = blockIdx.y * 128;
  const int s  = n0 >> 9;
  const int hh = ((n0 >> 6) + wn) & 7;
  f32x4 facc[4][4] = {};
  for (int kp = 0; kp < 4; ++kp) {
    f32x4 acc[4][4] = {};
    gemm_cv(xcat + kp * DM, XW, WvT_l, DM, As, Bs, acc);
    float wv[4][4];
#pragma unroll
    for (int m = 0; m < 4; ++m)
#pragma unroll
      for (int j = 0; j < 4; ++j) {
        const int gr = m0 + wm * 64 + m * 16 + (ln >> 4) * 4 + j;
        wv[m][j] = wbuf[(((size_t)s * NB + gr) * 8 + hh) * 4 + kp];
      }
#pragma unroll
    for (int n = 0; n < 4; ++n) {
      const float bvv = bv_l[n0 + wn * 64 + n * 16 + (ln & 15)];
#pragma unroll
      for (int m = 0; m < 4; ++m)
#pragma unroll
        for (int j = 0; j < 4; ++j)
          facc[m][n][j] += (acc[m][n][j] + bvv) * wv[m][j];
    }
  }
#pragma unroll
  for (int n = 0; n < 4; ++n) {
    const int gc = n0 + wn * 64 + n * 16 + (ln & 15);
#pragma unroll
    for (int m = 0; m < 4; ++m)
#pragma unroll
      for (int j = 0; j < 4; ++j) {
        const int gr = m0 + wm * 64 + m * 16 + (ln >> 4) * 4 + j;
        ctxc[(size_t)gr * XW + gc] = f2bf(facc[m][n][j]);
      }
  }
}

// softmax over kp in-place on wbuf [S][B][H][4]; optional write to attn0 [B][S][H][4]
__global__ __launch_bounds__(256) void k_softmax(
    float* __restrict__ wbuf, float* __restrict__ a0)
{
  const int t = blockIdx.x * 256 + threadIdx.x;   // (s*NB + b)*8 + h
  float4 v = ((const float4*)wbuf)[t];
  const float mx = fmaxf(fmaxf(v.x, v.y), fmaxf(v.z, v.w));
  float4 e;
  e.x = __expf(v.x - mx); e.y = __expf(v.y - mx);
  e.z = __expf(v.z - mx); e.w = __expf(v.w - mx);
  const float inv = 1.f / (e.x + e.y + e.z + e.w);
  e.x *= inv; e.y *= inv; e.z *= inv; e.w *= inv;
  ((float4*)wbuf)[t] = e;
  if (a0 != nullptr) {
    const int s = t >> 17, b = (t >> 3) & (NB - 1), h = t & 7;
    ((float4*)a0)[((size_t)b * NS + s) * 8 + h] = e;
  }
}

// in-place LayerNorm over each 512-wide stream block of xcat; wave per (b,s)
__global__ __launch_bounds__(256) void k_ln(
    u16* __restrict__ xcat, const float* __restrict__ g, const float* __restrict__ bb)
{
  const int ln = threadIdx.x & 63;
  const int row = blockIdx.x * 4 + (threadIdx.x >> 6);
  const int b = row >> 2, s = row & 3;
  u16* p = xcat + (size_t)b * XW + s * DM;
  float v[8];
  { uint4 t = ((const uint4*)p)[ln]; unpack8(t, v); }
  float sum = 0.f;
#pragma unroll
  for (int j = 0; j < 8; ++j) sum += v[j];
#pragma unroll
  for (int off = 1; off < 64; off <<= 1) sum += __shfl_xor(sum, off, 64);
  const float mu = sum * (1.f / DM);
  float s2 = 0.f;
#pragma unroll
  for (int j = 0; j < 8; ++j) { float d = v[j] - mu; s2 += d * d; }
#pragma unroll
  for (int off = 1; off < 64; off <<= 1) s2 += __shfl_xor(s2, off, 64);
  const float rs = rsqrtf(s2 * (1.f / DM) + EPSL);
  const int e0 = s * DM + ln * 8;
  float o[8];
#pragma unroll
  for (int j = 0; j < 8; ++j) o[j] = (v[j] - mu) * rs * g[e0 + j] + bb[e0 + j];
  ((uint4*)p)[ln] = pack8(o);
}

// pack 4 fp32 streams -> xcat bf16 [B][S*D]
__global__ void k_pack(const float* __restrict__ t0, const float* __restrict__ t1,
                       const float* __restrict__ t2, const float* __restrict__ t3,
                       u16* __restrict__ xcat)
{
  const int total = NB * XW / 8;
  for (int t = blockIdx.x * blockDim.x + threadIdx.x; t < total; t += gridDim.x * blockDim.x) {
    const int b = t >> 8;
    const int r = t & 255;
    const int s = r >> 6;
    const int d0 = (r & 63) * 8;
    const float* p = (s == 0) ? t0 : (s == 1) ? t1 : (s == 2) ? t2 : t3;
    float f[8];
#pragma unroll
    for (int j = 0; j < 8; ++j) f[j] = p[(size_t)b * DM + d0 + j];
    ((uint4*)xcat)[t] = pack8(f);
  }
}

// transpose + fp32->bf16: src nb x [R][C] -> dst nb x [C][R]; pow2 dims (pass logs)
__global__ void k_tcvt(const float* __restrict__ src, u16* __restrict__ dst,
                       int rlog, int clog, int nb)
{
  const int mlog = rlog + clog;
  const size_t total = (size_t)nb << mlog;
  for (size_t t = (size_t)blockIdx.x * blockDim.x + threadIdx.x; t < total;
       t += (size_t)gridDim.x * blockDim.x) {
    const size_t mat = t >> mlog;
    const uint32_t rem = (uint32_t)(t & ((1u << mlog) - 1));
    const uint32_t n = rem >> rlog;
    const uint32_t r = rem & ((1u << rlog) - 1);
    dst[t] = f2bf(src[(mat << mlog) + ((size_t)r << clog) + n]);
  }
}

extern "C" void kernel_launch(void* const* d_in, const int* in_sizes, int n_in,
                              void* d_out, int out_size, void* d_ws, size_t ws_size,
                              hipStream_t stream)
{
  (void)in_sizes; (void)n_in; (void)out_size;
  const float* t0  = (const float*)d_in[0];
  const float* t1  = (const float*)d_in[1];
  const float* t2  = (const float*)d_in[2];
  const float* t3  = (const float*)d_in[3];
  const float* Wq  = (const float*)d_in[4];
  const float* bq  = (const float*)d_in[5];
  const float* Wk  = (const float*)d_in[6];
  const float* Wv  = (const float*)d_in[8];
  const float* bv  = (const float*)d_in[9];
  const float* Wo  = (const float*)d_in[10];
  const float* bo  = (const float*)d_in[11];
  const float* lng = (const float*)d_in[12];
  const float* lnb = (const float*)d_in[13];
  const float* W1  = (const float*)d_in[14];
  const float* b1  = (const float*)d_in[15];
  const float* W2  = (const float*)d_in[16];
  const float* b2  = (const float*)d_in[17];
  const float* Wf1 = (const float*)d_in[18];
  const float* bf1 = (const float*)d_in[19];
  const float* Wf2 = (const float*)d_in[20];
  const float* bf2 = (const float*)d_in[21];

  size_t off = 0;
  char* ws = (char*)d_ws;
  auto take = [&](size_t n) { char* p = ws + off; off += (n + 255) & ~(size_t)255; return p; };
  u16* WqT  = (u16*)take(8ull * DM * DM * 2);        //  4 MiB
  u16* WkT  = (u16*)take(8ull * DM * DM * 2);        //  4
  u16* WvT  = (u16*)take(8ull * DM * DM * 2);        //  4
  u16* WoT  = (u16*)take(8ull * DM * DM * 2);        //  4
  u16* W1T  = (u16*)take(8ull * DM * FH * 2);        // 16
  u16* W2T  = (u16*)take(8ull * FH * DM * 2);        // 16
  u16* Wf1T = (u16*)take((size_t)XW * 1024 * 2);     //  4
  u16* Wf2T = (u16*)take((size_t)1024 * DM * 2);     //  1
  u16* xcat = (u16*)take((size_t)NB * XW * 2);       // 64
  char* U1  = take((size_t)NB * XW * 2);             // 64: Qb | ctxc | ffn1 | y1
  float* wbuf = (float*)take(4ull * NB * 8 * 4 * 4); //  8
  const size_t needed = off;                          // ~189 MiB

  u16* Qb   = (u16*)U1;   // [S][B][512]
  u16* ctxc = (u16*)U1;   // [B][2048]
  u16* ffn1 = (u16*)U1;   // [B][2048] per stream
  u16* y1   = (u16*)U1;   // [B][1024]
  float* attn0 = (float*)d_out + (size_t)NB * DM;

  if (needed > ws_size) return;  // diagnostic: clean fail instead of GPU fault

  // weight prep: fp32 -> bf16, transposed to [N][K]
  k_tcvt<<<dim3(1024), dim3(256), 0, stream>>>(Wq, WqT, 9, 9, 8);
  k_tcvt<<<dim3(1024), dim3(256), 0, stream>>>(Wk, WkT, 9, 9, 8);
  k_tcvt<<<dim3(1024), dim3(256), 0, stream>>>(Wv, WvT, 9, 9, 8);
  k_tcvt<<<dim3(1024), dim3(256), 0, stream>>>(Wo, WoT, 9, 9, 8);
  k_tcvt<<<dim3(1024), dim3(256), 0, stream>>>(W1, W1T, 9, 11, 8);
  k_tcvt<<<dim3(1024), dim3(256), 0, stream>>>(W2, W2T, 11, 9, 8);
  k_tcvt<<<dim3(1024), dim3(256), 0, stream>>>(Wf1, Wf1T, 11, 10, 1);
  k_tcvt<<<dim3(1024), dim3(256), 0, stream>>>(Wf2, Wf2T, 10, 9, 1);
  k_pack<<<dim3(2048), dim3(256), 0, stream>>>(t0, t1, t2, t3, xcat);

  const size_t WSQ = (size_t)DM * DM;
  for (int ly = 0; ly < 2; ++ly) {
    const u16* WqT_l = WqT + (size_t)ly * 4 * WSQ;
    const u16* WkT_l = WkT + (size_t)ly * 4 * WSQ;
    const u16* WvT_l = WvT + (size_t)ly * 4 * WSQ;
    const u16* WoT_l = WoT + (size_t)ly * 4 * WSQ;
    // Q projection, all streams in one launch (z = s)
    k_gemm<false, false, false><<<dim3(128, 4, 4), dim3(256), 0, stream>>>(
        xcat, XW, DM, WqT_l, WSQ, bq + (size_t)ly * XW, DM,
        nullptr, 0, 0, Qb, DM, (long)NB * DM, DM);
    // K projection + fused q.k dot, all (s,kp) in one launch
    k_kdot<<<dim3(128, 4, 16), dim3(256), 0, stream>>>(xcat, WkT_l, Qb, wbuf);
    k_softmax<<<dim3(4 * NB * 8 / 256), dim3(256), 0, stream>>>(
        wbuf, (ly == 0) ? attn0 : (float*)nullptr);
    // V projection (N=2048 over streams), all 4 kp fused, fp32 reg accumulate
    k_gemmv4<<<dim3(128, 16), dim3(256), 0, stream>>>(
        xcat, WvT_l, bv + (size_t)ly * XW, wbuf, ctxc);
    // O projection, residual-fused, in-place into xcat (z = s)
    k_gemm<false, true, false><<<dim3(128, 4, 4), dim3(256), 0, stream>>>(
        ctxc, XW, DM, WoT_l, WSQ, bo + (size_t)ly * XW, DM,
        xcat, XW, DM, xcat, XW, DM, DM);
    k_ln<<<dim3(NB), dim3(256), 0, stream>>>(xcat, lng + ly * XW, lnb + ly * XW);
    // FFN per stream, residual-fused, in-place into xcat
    for (int s = 0; s < NS; ++s) {
      const size_t wsl = (size_t)(ly * 4 + s);
      k_gemm<true, false, false><<<dim3(128, 16, 1), dim3(256), 0, stream>>>(
          xcat + s * DM, XW, 0, W1T + wsl * (size_t)DM * FH, 0, b1 + wsl * FH, 0,
          nullptr, 0, 0, ffn1, FH, 0, DM);
      k_gemm<false, true, false><<<dim3(128, 4, 1), dim3(256), 0, stream>>>(
          ffn1, FH, 0, W2T + wsl * (size_t)FH * DM, 0, b2 + wsl * DM, 0,
          xcat + s * DM, XW, 0, xcat + s * DM, XW, 0, FH);
    }
  }
  // final fusion MLP
  k_gemm<true, false, false><<<dim3(128, 8, 1), dim3(256), 0, stream>>>(
      xcat, XW, 0, Wf1T, 0, bf1, 0, nullptr, 0, 0, y1, 1024, 0, XW);
  k_gemm<false, false, true><<<dim3(128, 4, 1), dim3(256), 0, stream>>>(
      y1, 1024, 0, Wf2T, 0, bf2, 0, nullptr, 0, 0, d_out, DM, 0, 1024);
}

// Round 5
// 2551.168 us; speedup vs baseline: 1.4867x; 1.0583x over previous
//
#include <hip/hip_runtime.h>
#include <stdint.h>

typedef unsigned short u16;
typedef __bf16 bf16x8 __attribute__((ext_vector_type(8)));
typedef float f32x4 __attribute__((ext_vector_type(4)));

constexpr int NB = 16384;        // batch tokens
constexpr int DM = 512;          // model dim
constexpr int NS = 4;            // streams
constexpr int FH = 2048;         // FFN hidden
constexpr int XW = NS * DM;      // 2048 concat width
constexpr float EPSL = 1e-5f;

__device__ __forceinline__ float bf2f(u16 u) { return __uint_as_float(((uint32_t)u) << 16); }
__device__ __forceinline__ u16 f2bf(float f) {
  uint32_t u = __float_as_uint(f);
  u += 0x7fffu + ((u >> 16) & 1u);
  return (u16)(u >> 16);
}
__device__ __forceinline__ void unpack8(uint4 p, float* f) {
  f[0] = __uint_as_float(p.x << 16); f[1] = __uint_as_float(p.x & 0xffff0000u);
  f[2] = __uint_as_float(p.y << 16); f[3] = __uint_as_float(p.y & 0xffff0000u);
  f[4] = __uint_as_float(p.z << 16); f[5] = __uint_as_float(p.z & 0xffff0000u);
  f[6] = __uint_as_float(p.w << 16); f[7] = __uint_as_float(p.w & 0xffff0000u);
}
__device__ __forceinline__ uint4 pack8(const float* f) {
  uint4 r;
  r.x = (uint32_t)f2bf(f[0]) | ((uint32_t)f2bf(f[1]) << 16);
  r.y = (uint32_t)f2bf(f[2]) | ((uint32_t)f2bf(f[3]) << 16);
  r.z = (uint32_t)f2bf(f[4]) | ((uint32_t)f2bf(f[5]) << 16);
  r.w = (uint32_t)f2bf(f[6]) | ((uint32_t)f2bf(f[7]) << 16);
  return r;
}
__device__ __forceinline__ void gl_lds16(const void* g, void* l) {
  __builtin_amdgcn_global_load_lds((const __attribute__((address_space(1))) void*)g,
                                   (__attribute__((address_space(3))) void*)l, 16, 0, 0);
}

// XCD-aware 2-D block remap (T1 adapted). gx MUST be 128. HW round-robins the
// flat workgroup id over 8 XCDs (xcd = flat & 7). Remap so the ~64 blocks
// co-resident on one XCD cover 16 fixed bx values (A-slices, ~2 MB) and a
// sliding window of by values (B-tiles) -> staging working set fits 4 MiB L2.
// Bijective: flat = (by*16 + bx%16)*8 + bx/16.
__device__ __forceinline__ void xcd_remap(int& bx, int& by) {
  const int flat = blockIdx.y * 128 + blockIdx.x;
  const int xcd = flat & 7;
  const int t = flat >> 3;
  bx = xcd * 16 + (t & 15);
  by = t >> 4;
}

// ---- counted-vmcnt 3-buffer GEMM core: 128x128 tile, BK=32, 256 threads ----
// LDS write-linear for global_load_lds; GLOBAL source 16B-block pre-permuted
// blk^=(row>>1)&3, reads apply the same XOR -> even bank spread (conflict-free).
// Pipeline: stage tile t+2 during compute of t; vmcnt(4) + raw s_barrier.
__device__ __forceinline__ void gemm_cv(
    const u16* __restrict__ A, int lda,
    const u16* __restrict__ Bt, int K,    // Bt row stride == K
    u16* As, u16* Bs, f32x4 (&acc)[4][4], int bx, int by)
{
  const int tid = threadIdx.x;
  const int ln = tid & 63;
  const int w  = tid >> 6;
  const int wm = w >> 1, wn = w & 1;
  const int m0 = bx * 128;
  const int n0 = by * 128;
  const int grow = ln >> 2;                                  // row within 16-chunk
  const int gcol = ((ln & 3) ^ ((ln >> 3) & 3)) * 8;         // swizzled src 16B-block
  const u16* Ab = A  + (size_t)(m0 + w * 32 + grow) * lda + gcol;
  const u16* Bb = Bt + (size_t)(n0 + w * 32 + grow) * K   + gcol;

  auto stage = [&](int buf, int k0) {
#pragma unroll
    for (int i = 0; i < 2; ++i) {
      gl_lds16(Ab + (size_t)i * 16 * lda + k0, &As[buf * 4096 + (w * 32 + i * 16) * 32]);
      gl_lds16(Bb + (size_t)i * 16 * K   + k0, &Bs[buf * 4096 + (w * 32 + i * 16) * 32]);
    }
  };

  __syncthreads();               // protect LDS reuse across successive calls
  const int nt = K >> 5;
  stage(0, 0);
  if (nt > 1) {
    stage(1, 32);
    asm volatile("s_waitcnt vmcnt(4)" ::: "memory");
  } else {
    asm volatile("s_waitcnt vmcnt(0)" ::: "memory");
  }
  __builtin_amdgcn_s_barrier();
  asm volatile("" ::: "memory");

  const int rx = ((ln & 15) >> 1) & 3;   // per-row read XOR
  const int qb = ln >> 4;
  const int cb = (qb ^ rx) * 8;          // swizzled read 16B-block (elems)
  int cur = 0, nxt2 = 2;
  for (int t = 0; t < nt; ++t) {
    bf16x8 af[4], bfv[4];
#pragma unroll
    for (int m = 0; m < 4; ++m) {
      af[m]  = *(const bf16x8*)&As[cur * 4096 + (wm * 64 + m * 16 + (ln & 15)) * 32 + cb];
      bfv[m] = *(const bf16x8*)&Bs[cur * 4096 + (wn * 64 + m * 16 + (ln & 15)) * 32 + cb];
    }
#pragma unroll
    for (int m = 0; m < 4; ++m)
#pragma unroll
      for (int n = 0; n < 4; ++n)
        acc[m][n] = __builtin_amdgcn_mfma_f32_16x16x32_bf16(af[m], bfv[n], acc[m][n], 0, 0, 0);
    if (t + 2 < nt) {
      stage(nxt2, (t + 2) * 32);
      asm volatile("s_waitcnt vmcnt(4)" ::: "memory");   // tile t+1 ready, t+2 in flight
      __builtin_amdgcn_s_barrier();
      asm volatile("" ::: "memory");
    } else if (t + 1 < nt) {
      asm volatile("s_waitcnt vmcnt(0)" ::: "memory");   // drain last tile
      __builtin_amdgcn_s_barrier();
      asm volatile("" ::: "memory");
    }
    cur = cur + 1;  if (cur == 3)  cur = 0;
    nxt2 = nxt2 + 1; if (nxt2 == 3) nxt2 = 0;
  }
  asm volatile("" ::: "memory");   // fence: epilogue vmem must not hoist into loop
}

// generic GEMM with per-z offsets: C = A*Bt^T + bias [+Rsd][ReLU]
template<bool RELU, bool RESID, bool OUTF32>
__global__ __launch_bounds__(256) void k_gemm(
    const u16* __restrict__ A, int lda, long aZ,
    const u16* __restrict__ Bt, long bZ,
    const float* __restrict__ bias, long biasZ,
    const u16* __restrict__ Rsd, int ldr, long rZ,
    void* __restrict__ Cp, int ldc, long cZ, int K)
{
  const int z = blockIdx.z;
  A += (long)z * aZ; Bt += (long)z * bZ; bias += (long)z * biasZ;
  int bx, by; xcd_remap(bx, by);
  __shared__ alignas(16) u16 As[3 * 4096];
  __shared__ alignas(16) u16 Bs[3 * 4096];
  f32x4 acc[4][4] = {};
  gemm_cv(A, lda, Bt, K, As, Bs, acc, bx, by);
  const int ln = threadIdx.x & 63;
  const int w = threadIdx.x >> 6;
  const int wm = w >> 1, wn = w & 1;
  const int m0 = bx * 128, n0 = by * 128;
#pragma unroll
  for (int n = 0; n < 4; ++n) {
    const int gc = n0 + wn * 64 + n * 16 + (ln & 15);
    const float bv = bias[gc];
#pragma unroll
    for (int m = 0; m < 4; ++m) {
#pragma unroll
      for (int j = 0; j < 4; ++j) {
        const int gr = m0 + wm * 64 + m * 16 + (ln >> 4) * 4 + j;
        float v = acc[m][n][j] + bv;
        if constexpr (RESID) v += bf2f(Rsd[(long)z * rZ + (size_t)gr * ldr + gc]);
        if constexpr (RELU)  v = v > 0.f ? v : 0.f;
        if constexpr (OUTF32) ((float*)Cp)[(long)z * cZ + (size_t)gr * ldc + gc] = v;
        else                  ((u16*)Cp)[(long)z * cZ + (size_t)gr * ldc + gc] = f2bf(v);
      }
    }
  }
}

// K-projection GEMM with fused q.k dot epilogue. z = s*4+kp.
// Writes raw scores (x1/8) to wbuf[s][b][h][kp]. K-bias softmax-invariant, dropped.
__global__ __launch_bounds__(256) void k_kdot(
    const u16* __restrict__ xcat, const u16* __restrict__ WkT_l,
    const u16* __restrict__ Qb, float* __restrict__ wbuf)
{
  const int s = blockIdx.z >> 2, kp = blockIdx.z & 3;
  int bx, by; xcd_remap(bx, by);
  __shared__ alignas(16) u16 As[3 * 4096];
  __shared__ alignas(16) u16 Bs[3 * 4096];
  f32x4 acc[4][4] = {};
  gemm_cv(xcat + kp * DM, XW, WkT_l + (size_t)s * DM * DM, DM, As, Bs, acc, bx, by);
  const int ln = threadIdx.x & 63;
  const int w = threadIdx.x >> 6;
  const int wm = w >> 1, wn = w & 1;
  const int m0 = bx * 128, n0 = by * 128;
  const int h = (n0 >> 6) + wn;
  float p[4][4];
#pragma unroll
  for (int m = 0; m < 4; ++m)
#pragma unroll
    for (int j = 0; j < 4; ++j) p[m][j] = 0.f;
#pragma unroll
  for (int n = 0; n < 4; ++n) {
    const int gc = n0 + wn * 64 + n * 16 + (ln & 15);
#pragma unroll
    for (int m = 0; m < 4; ++m) {
#pragma unroll
      for (int j = 0; j < 4; ++j) {
        const int gr = m0 + wm * 64 + m * 16 + (ln >> 4) * 4 + j;
        p[m][j] += acc[m][n][j] * bf2f(Qb[((size_t)s * NB + gr) * DM + gc]);
      }
    }
  }
#pragma unroll
  for (int m = 0; m < 4; ++m)
#pragma unroll
    for (int j = 0; j < 4; ++j) {
      float v = p[m][j];
      v += __shfl_xor(v, 1, 64);
      v += __shfl_xor(v, 2, 64);
      v += __shfl_xor(v, 4, 64);
      v += __shfl_xor(v, 8, 64);
      p[m][j] = v;
    }
  if ((ln & 15) == 0) {
#pragma unroll
    for (int m = 0; m < 4; ++m)
#pragma unroll
      for (int j = 0; j < 4; ++j) {
        const int gr = m0 + wm * 64 + m * 16 + (ln >> 4) * 4 + j;
        wbuf[(((size_t)s * NB + gr) * 8 + h) * 4 + kp] = p[m][j] * 0.125f;
      }
  }
}

// V-projection for all 4 key positions fused: facc = sum_kp w[s,b,h,kp]*((x_kp Wv)_gc + bv)
// single bf16 write of ctxc [B][2048]; softmax weights read between phases (vmem-clean).
__global__ __launch_bounds__(256) void k_gemmv4(
    const u16* __restrict__ xcat, const u16* __restrict__ WvT_l,
    const float* __restrict__ bv_l, const float* __restrict__ wbuf,
    u16* __restrict__ ctxc)
{
  int bx, by; xcd_remap(bx, by);
  __shared__ alignas(16) u16 As[3 * 4096];
  __shared__ alignas(16) u16 Bs[3 * 4096];
  const int ln = threadIdx.x & 63;
  const int w = threadIdx.x >> 6;
  const int wm = w >> 1, wn = w & 1;
  const int m0 = bx * 128, n0 = by * 128;
  const int s  = n0 >> 9;
  const int hh = ((n0 >> 6) + wn) & 7;
  f32x4 facc[4][4] = {};
  for (int kp = 0; kp < 4; ++kp) {
    f32x4 acc[4][4] = {};
    gemm_cv(xcat + kp * DM, XW, WvT_l, DM, As, Bs, acc, bx, by);
    float wv[4][4];
#pragma unroll
    for (int m = 0; m < 4; ++m)
#pragma unroll
      for (int j = 0; j < 4; ++j) {
        const int gr = m0 + wm * 64 + m * 16 + (ln >> 4) * 4 + j;
        wv[m][j] = wbuf[(((size_t)s * NB + gr) * 8 + hh) * 4 + kp];
      }
#pragma unroll
    for (int n = 0; n < 4; ++n) {
      const float bvv = bv_l[n0 + wn * 64 + n * 16 + (ln & 15)];
#pragma unroll
      for (int m = 0; m < 4; ++m)
#pragma unroll
        for (int j = 0; j < 4; ++j)
          facc[m][n][j] += (acc[m][n][j] + bvv) * wv[m][j];
    }
  }
#pragma unroll
  for (int n = 0; n < 4; ++n) {
    const int gc = n0 + wn * 64 + n * 16 + (ln & 15);
#pragma unroll
    for (int m = 0; m < 4; ++m)
#pragma unroll
      for (int j = 0; j < 4; ++j) {
        const int gr = m0 + wm * 64 + m * 16 + (ln >> 4) * 4 + j;
        ctxc[(size_t)gr * XW + gc] = f2bf(facc[m][n][j]);
      }
  }
}

// softmax over kp in-place on wbuf [S][B][H][4]; optional write to attn0 [B][S][H][4]
__global__ __launch_bounds__(256) void k_softmax(
    float* __restrict__ wbuf, float* __restrict__ a0)
{
  const int t = blockIdx.x * 256 + threadIdx.x;   // (s*NB + b)*8 + h
  float4 v = ((const float4*)wbuf)[t];
  const float mx = fmaxf(fmaxf(v.x, v.y), fmaxf(v.z, v.w));
  float4 e;
  e.x = __expf(v.x - mx); e.y = __expf(v.y - mx);
  e.z = __expf(v.z - mx); e.w = __expf(v.w - mx);
  const float inv = 1.f / (e.x + e.y + e.z + e.w);
  e.x *= inv; e.y *= inv; e.z *= inv; e.w *= inv;
  ((float4*)wbuf)[t] = e;
  if (a0 != nullptr) {
    const int s = t >> 17, b = (t >> 3) & (NB - 1), h = t & 7;
    ((float4*)a0)[((size_t)b * NS + s) * 8 + h] = e;
  }
}

// in-place LayerNorm over each 512-wide stream block of xcat; wave per (b,s)
__global__ __launch_bounds__(256) void k_ln(
    u16* __restrict__ xcat, const float* __restrict__ g, const float* __restrict__ bb)
{
  const int ln = threadIdx.x & 63;
  const int row = blockIdx.x * 4 + (threadIdx.x >> 6);
  const int b = row >> 2, s = row & 3;
  u16* p = xcat + (size_t)b * XW + s * DM;
  float v[8];
  { uint4 t = ((const uint4*)p)[ln]; unpack8(t, v); }
  float sum = 0.f;
#pragma unroll
  for (int j = 0; j < 8; ++j) sum += v[j];
#pragma unroll
  for (int off = 1; off < 64; off <<= 1) sum += __shfl_xor(sum, off, 64);
  const float mu = sum * (1.f / DM);
  float s2 = 0.f;
#pragma unroll
  for (int j = 0; j < 8; ++j) { float d = v[j] - mu; s2 += d * d; }
#pragma unroll
  for (int off = 1; off < 64; off <<= 1) s2 += __shfl_xor(s2, off, 64);
  const float rs = rsqrtf(s2 * (1.f / DM) + EPSL);
  const int e0 = s * DM + ln * 8;
  float o[8];
#pragma unroll
  for (int j = 0; j < 8; ++j) o[j] = (v[j] - mu) * rs * g[e0 + j] + bb[e0 + j];
  ((uint4*)p)[ln] = pack8(o);
}

// pack 4 fp32 streams -> xcat bf16 [B][S*D]
__global__ void k_pack(const float* __restrict__ t0, const float* __restrict__ t1,
                       const float* __restrict__ t2, const float* __restrict__ t3,
                       u16* __restrict__ xcat)
{
  const int total = NB * XW / 8;
  for (int t = blockIdx.x * blockDim.x + threadIdx.x; t < total; t += gridDim.x * blockDim.x) {
    const int b = t >> 8;
    const int r = t & 255;
    const int s = r >> 6;
    const int d0 = (r & 63) * 8;
    const float* p = (s == 0) ? t0 : (s == 1) ? t1 : (s == 2) ? t2 : t3;
    float f[8];
#pragma unroll
    for (int j = 0; j < 8; ++j) f[j] = p[(size_t)b * DM + d0 + j];
    ((uint4*)xcat)[t] = pack8(f);
  }
}

// transpose + fp32->bf16: src nb x [R][C] -> dst nb x [C][R]; pow2 dims (pass logs)
__global__ void k_tcvt(const float* __restrict__ src, u16* __restrict__ dst,
                       int rlog, int clog, int nb)
{
  const int mlog = rlog + clog;
  const size_t total = (size_t)nb << mlog;
  for (size_t t = (size_t)blockIdx.x * blockDim.x + threadIdx.x; t < total;
       t += (size_t)gridDim.x * blockDim.x) {
    const size_t mat = t >> mlog;
    const uint32_t rem = (uint32_t)(t & ((1u << mlog) - 1));
    const uint32_t n = rem >> rlog;
    const uint32_t r = rem & ((1u << rlog) - 1);
    dst[t] = f2bf(src[(mat << mlog) + ((size_t)r << clog) + n]);
  }
}

extern "C" void kernel_launch(void* const* d_in, const int* in_sizes, int n_in,
                              void* d_out, int out_size, void* d_ws, size_t ws_size,
                              hipStream_t stream)
{
  (void)in_sizes; (void)n_in; (void)out_size;
  const float* t0  = (const float*)d_in[0];
  const float* t1  = (const float*)d_in[1];
  const float* t2  = (const float*)d_in[2];
  const float* t3  = (const float*)d_in[3];
  const float* Wq  = (const float*)d_in[4];
  const float* bq  = (const float*)d_in[5];
  const float* Wk  = (const float*)d_in[6];
  const float* Wv  = (const float*)d_in[8];
  const float* bv  = (const float*)d_in[9];
  const float* Wo  = (const float*)d_in[10];
  const float* bo  = (const float*)d_in[11];
  const float* lng = (const float*)d_in[12];
  const float* lnb = (const float*)d_in[13];
  const float* W1  = (const float*)d_in[14];
  const float* b1  = (const float*)d_in[15];
  const float* W2  = (const float*)d_in[16];
  const float* b2  = (const float*)d_in[17];
  const float* Wf1 = (const float*)d_in[18];
  const float* bf1 = (const float*)d_in[19];
  const float* Wf2 = (const float*)d_in[20];
  const float* bf2 = (const float*)d_in[21];

  size_t off = 0;
  char* ws = (char*)d_ws;
  auto take = [&](size_t n) { char* p = ws + off; off += (n + 255) & ~(size_t)255; return p; };
  u16* WqT  = (u16*)take(8ull * DM * DM * 2);        //  4 MiB
  u16* WkT  = (u16*)take(8ull * DM * DM * 2);        //  4
  u16* WvT  = (u16*)take(8ull * DM * DM * 2);        //  4
  u16* WoT  = (u16*)take(8ull * DM * DM * 2);        //  4
  u16* W1T  = (u16*)take(8ull * DM * FH * 2);        // 16
  u16* W2T  = (u16*)take(8ull * FH * DM * 2);        // 16
  u16* Wf1T = (u16*)take((size_t)XW * 1024 * 2);     //  4
  u16* Wf2T = (u16*)take((size_t)1024 * DM * 2);     //  1
  u16* xcat = (u16*)take((size_t)NB * XW * 2);       // 64
  char* U1  = take((size_t)NB * XW * 2);             // 64: Qb | ctxc | ffn1 | y1
  float* wbuf = (float*)take(4ull * NB * 8 * 4 * 4); //  8
  const size_t needed = off;                          // ~189 MiB

  u16* Qb   = (u16*)U1;   // [S][B][512]
  u16* ctxc = (u16*)U1;   // [B][2048]
  u16* ffn1 = (u16*)U1;   // [B][2048] per stream
  u16* y1   = (u16*)U1;   // [B][1024]
  float* attn0 = (float*)d_out + (size_t)NB * DM;

  if (needed > ws_size) return;  // diagnostic: clean fail instead of GPU fault

  // weight prep: fp32 -> bf16, transposed to [N][K]
  k_tcvt<<<dim3(1024), dim3(256), 0, stream>>>(Wq, WqT, 9, 9, 8);
  k_tcvt<<<dim3(1024), dim3(256), 0, stream>>>(Wk, WkT, 9, 9, 8);
  k_tcvt<<<dim3(1024), dim3(256), 0, stream>>>(Wv, WvT, 9, 9, 8);
  k_tcvt<<<dim3(1024), dim3(256), 0, stream>>>(Wo, WoT, 9, 9, 8);
  k_tcvt<<<dim3(1024), dim3(256), 0, stream>>>(W1, W1T, 9, 11, 8);
  k_tcvt<<<dim3(1024), dim3(256), 0, stream>>>(W2, W2T, 11, 9, 8);
  k_tcvt<<<dim3(1024), dim3(256), 0, stream>>>(Wf1, Wf1T, 11, 10, 1);
  k_tcvt<<<dim3(1024), dim3(256), 0, stream>>>(Wf2, Wf2T, 10, 9, 1);
  k_pack<<<dim3(2048), dim3(256), 0, stream>>>(t0, t1, t2, t3, xcat);

  const size_t WSQ = (size_t)DM * DM;
  for (int ly = 0; ly < 2; ++ly) {
    const u16* WqT_l = WqT + (size_t)ly * 4 * WSQ;
    const u16* WkT_l = WkT + (size_t)ly * 4 * WSQ;
    const u16* WvT_l = WvT + (size_t)ly * 4 * WSQ;
    const u16* WoT_l = WoT + (size_t)ly * 4 * WSQ;
    // Q projection, all streams in one launch (z = s)
    k_gemm<false, false, false><<<dim3(128, 4, 4), dim3(256), 0, stream>>>(
        xcat, XW, DM, WqT_l, WSQ, bq + (size_t)ly * XW, DM,
        nullptr, 0, 0, Qb, DM, (long)NB * DM, DM);
    // K projection + fused q.k dot, all (s,kp) in one launch
    k_kdot<<<dim3(128, 4, 16), dim3(256), 0, stream>>>(xcat, WkT_l, Qb, wbuf);
    k_softmax<<<dim3(4 * NB * 8 / 256), dim3(256), 0, stream>>>(
        wbuf, (ly == 0) ? attn0 : (float*)nullptr);
    // V projection (N=2048 over streams), all 4 kp fused, fp32 reg accumulate
    k_gemmv4<<<dim3(128, 16), dim3(256), 0, stream>>>(
        xcat, WvT_l, bv + (size_t)ly * XW, wbuf, ctxc);
    // O projection, residual-fused, in-place into xcat (z = s)
    k_gemm<false, true, false><<<dim3(128, 4, 4), dim3(256), 0, stream>>>(
        ctxc, XW, DM, WoT_l, WSQ, bo + (size_t)ly * XW, DM,
        xcat, XW, DM, xcat, XW, DM, DM);
    k_ln<<<dim3(NB), dim3(256), 0, stream>>>(xcat, lng + ly * XW, lnb + ly * XW);
    // FFN per stream, residual-fused, in-place into xcat
    for (int s = 0; s < NS; ++s) {
      const size_t wsl = (size_t)(ly * 4 + s);
      k_gemm<true, false, false><<<dim3(128, 16, 1), dim3(256), 0, stream>>>(
          xcat + s * DM, XW, 0, W1T + wsl * (size_t)DM * FH, 0, b1 + wsl * FH, 0,
          nullptr, 0, 0, ffn1, FH, 0, DM);
      k_gemm<false, true, false><<<dim3(128, 4, 1), dim3(256), 0, stream>>>(
          ffn1, FH, 0, W2T + wsl * (size_t)FH * DM, 0, b2 + wsl * DM, 0,
          xcat + s * DM, XW, 0, xcat + s * DM, XW, 0, FH);
    }
  }
  // final fusion MLP
  k_gemm<true, false, false><<<dim3(128, 8, 1), dim3(256), 0, stream>>>(
      xcat, XW, 0, Wf1T, 0, bf1, 0, nullptr, 0, 0, y1, 1024, 0, XW);
  k_gemm<false, false, true><<<dim3(128, 4, 1), dim3(256), 0, stream>>>(
      y1, 1024, 0, Wf2T, 0, bf2, 0, nullptr, 0, 0, d_out, DM, 0, 1024);
}